// Round 4
// baseline (1608.670 us; speedup 1.0000x reference)
//
#include <hip/hip_runtime.h>
#include <hip/hip_fp16.h>
#include <type_traits>

#define N_NODES 100000
#define N_EDGES 1600000
#define NFEAT 512
#define NHID 256
#define NCLASS 40
#define NPAD 100096   // 391 * 256
#define NB 391

typedef __bf16 bf16;
typedef __bf16 bf16x8 __attribute__((ext_vector_type(8)));
typedef float f32x4 __attribute__((ext_vector_type(4)));

// ---------------- CSR build ----------------

__global__ void init_cnt(int* cnt) {
    int i = blockIdx.x * 256 + threadIdx.x;
    if (i < NPAD) cnt[i] = 0;
}

__global__ void count_edges(const int* __restrict__ rows, int* __restrict__ cnt) {
    int e = blockIdx.x * 256 + threadIdx.x;
    if (e < N_EDGES) atomicAdd(&cnt[rows[e]], 1);
}

__global__ void reduce_blocks(const int* __restrict__ cnt, int* __restrict__ bsum) {
    __shared__ int sh[256];
    int t = threadIdx.x;
    sh[t] = cnt[blockIdx.x * 256 + t];
    __syncthreads();
    for (int off = 128; off > 0; off >>= 1) {
        if (t < off) sh[t] += sh[t + off];
        __syncthreads();
    }
    if (t == 0) bsum[blockIdx.x] = sh[0];
}

__global__ void scan_bsums(int* bsum) {
    __shared__ int sh[512];
    int t = threadIdx.x;
    int v = (t < NB) ? bsum[t] : 0;
    sh[t] = v;
    __syncthreads();
    for (int off = 1; off < 512; off <<= 1) {
        int x = (t >= off) ? sh[t - off] : 0;
        __syncthreads();
        sh[t] += x;
        __syncthreads();
    }
    if (t < NB) bsum[t] = sh[t] - v;  // exclusive
}

__global__ void scan_write(const int* __restrict__ cnt, const int* __restrict__ bsum,
                           int* __restrict__ rowptr, int* __restrict__ cursor,
                           float* __restrict__ dinv) {
    __shared__ int sh[256];
    int t = threadIdx.x, b = blockIdx.x;
    int i = b * 256 + t;
    int v = cnt[i];
    sh[t] = v;
    __syncthreads();
    for (int off = 1; off < 256; off <<= 1) {
        int x = (t >= off) ? sh[t - off] : 0;
        __syncthreads();
        sh[t] += x;
        __syncthreads();
    }
    int rp = bsum[b] + sh[t] - v;  // exclusive prefix
    rowptr[i] = rp;
    if (i < N_NODES) {
        cursor[i] = rp;
        dinv[i] = 1.0f / (float)(v + 1);  // +1 self-loop
    }
}

__global__ void scatter_edges(const int* __restrict__ rows, const int* __restrict__ cols,
                              int* __restrict__ cursor, int* __restrict__ colidx) {
    int e = blockIdx.x * 256 + threadIdx.x;
    if (e < N_EDGES) {
        int r = rows[e];
        int pos = atomicAdd(&cursor[r], 1);
        colidx[pos] = cols[e];
    }
}

// ---------------- weight conversion ----------------

__global__ void cvt_f2b(const float* __restrict__ a, bf16* __restrict__ b, int n) {
    int i = blockIdx.x * 256 + threadIdx.x;
    if (i < n) b[i] = (bf16)a[i];
}

__global__ void pad_w3(const float* __restrict__ W3, const float* __restrict__ b3,
                       bf16* __restrict__ W3p, float* __restrict__ b3p) {
    int i = blockIdx.x * 256 + threadIdx.x;  // over 64*256
    int r = i >> 8;
    W3p[i] = (bf16)((r < NCLASS) ? W3[(size_t)r * 256 + (i & 255)] : 0.f);
    if (i < 64) b3p[i] = (i < NCLASS) ? b3[i] : 0.f;
}

// ---------------- bf16 MFMA GEMM-NT with register-prefetch double buffer ----------------
// C[M,Nout] = A[M,K] @ B[Nout,K]^T + bias. A fp32 or bf16 (cvt at LDS-store time).
// OUTMODE 0: bf16 out [M,Nout]. OUTMODE 1: fp32 out [M,40] (cols >= 40 dropped).

template <int BN, typename AT, bool RELU, int OUTMODE>
__global__ __launch_bounds__(256) void gemm_mfma(const AT* __restrict__ A,
                                                 const bf16* __restrict__ B,
                                                 const float* __restrict__ bias,
                                                 bf16* __restrict__ Cb,
                                                 float* __restrict__ Cf,
                                                 int M, int K, int Nout) {
    constexpr int LDT = 56;                      // padded LDS row (bf16)
    constexpr int WTM = (BN == 128) ? 64 : 32;   // wave tile M
    constexpr int MI = WTM / 16;
    constexpr int WMC = 128 / WTM;               // waves along M
    constexpr int BG = BN / 64;
    __shared__ bf16 As[128 * LDT];
    __shared__ bf16 Bs[BN * LDT];

    int tid = threadIdx.x;
    int wave = tid >> 6, lane = tid & 63;
    int waveM = wave % WMC, waveN = wave / WMC;
    int lc = lane & 15, lq = lane >> 4;

    f32x4 acc[MI][4];
#pragma unroll
    for (int i = 0; i < MI; i++)
#pragma unroll
        for (int j = 0; j < 4; j++) acc[i][j] = (f32x4){0.f, 0.f, 0.f, 0.f};

    int sr = tid >> 2;           // staging row base
    int sc = (tid & 3) * 8;      // staging col (8 elements)

    // prefetch registers
    float4 fA[2][2];             // used when AT == float
    bf16x8 bA[2];                // used when AT == bf16
    bf16x8 bB[BG];
    bool rowok[2];

    auto ldA = [&](int k0) {
#pragma unroll
        for (int g = 0; g < 2; g++) {
            int grow = blockIdx.y * 128 + sr + g * 64;
            rowok[g] = (grow < M);
            if constexpr (std::is_same<AT, float>::value) {
                if (rowok[g]) {
                    const float* ap = A + (size_t)grow * K + k0 + sc;
                    fA[g][0] = *(const float4*)ap;
                    fA[g][1] = *(const float4*)(ap + 4);
                }
            } else {
                if (rowok[g]) bA[g] = *(const bf16x8*)(A + (size_t)grow * K + k0 + sc);
            }
        }
    };
    auto ldB = [&](int k0) {
#pragma unroll
        for (int g = 0; g < BG; g++) {
            int brow = blockIdx.x * BN + sr + g * 64;
            bB[g] = *(const bf16x8*)(B + (size_t)brow * K + k0 + sc);
        }
    };
    auto stTiles = [&]() {
#pragma unroll
        for (int g = 0; g < 2; g++) {
            bf16x8 val = (bf16x8){};
            if constexpr (std::is_same<AT, float>::value) {
                if (rowok[g]) {
                    val[0] = (bf16)fA[g][0].x; val[1] = (bf16)fA[g][0].y;
                    val[2] = (bf16)fA[g][0].z; val[3] = (bf16)fA[g][0].w;
                    val[4] = (bf16)fA[g][1].x; val[5] = (bf16)fA[g][1].y;
                    val[6] = (bf16)fA[g][1].z; val[7] = (bf16)fA[g][1].w;
                }
            } else {
                if (rowok[g]) val = bA[g];
            }
            *(bf16x8*)&As[(sr + g * 64) * LDT + sc] = val;
        }
#pragma unroll
        for (int g = 0; g < BG; g++)
            *(bf16x8*)&Bs[(sr + g * 64) * LDT + sc] = bB[g];
    };

    ldA(0);
    ldB(0);
    for (int k0 = 0; k0 < K; k0 += 32) {
        stTiles();
        __syncthreads();
        if (k0 + 32 < K) { ldA(k0 + 32); ldB(k0 + 32); }  // overlap with MFMA phase

        bf16x8 af[MI], bfr[4];
#pragma unroll
        for (int i = 0; i < MI; i++)
            af[i] = *(const bf16x8*)&As[(waveM * WTM + i * 16 + lc) * LDT + lq * 8];
#pragma unroll
        for (int j = 0; j < 4; j++)
            bfr[j] = *(const bf16x8*)&Bs[(waveN * 64 + j * 16 + lc) * LDT + lq * 8];
#pragma unroll
        for (int i = 0; i < MI; i++)
#pragma unroll
            for (int j = 0; j < 4; j++)
                acc[i][j] = __builtin_amdgcn_mfma_f32_16x16x32_bf16(af[i], bfr[j], acc[i][j], 0, 0, 0);
        __syncthreads();
    }

    // epilogue
#pragma unroll
    for (int i = 0; i < MI; i++) {
        int row0 = blockIdx.y * 128 + waveM * WTM + i * 16 + lq * 4;
#pragma unroll
        for (int j = 0; j < 4; j++) {
            int colL = waveN * 64 + j * 16 + lc;
            int col = blockIdx.x * BN + colL;
            float bv = bias[col];
#pragma unroll
            for (int reg = 0; reg < 4; reg++) {
                int rr = row0 + reg;
                if (rr < M) {
                    float v = acc[i][j][reg] + bv;
                    if (RELU) v = v > 0.f ? v : 0.f;
                    if (OUTMODE == 0) {
                        Cb[(size_t)rr * Nout + col] = (bf16)v;
                    } else {
                        if (col < NCLASS) Cf[(size_t)rr * NCLASS + col] = v;
                    }
                }
            }
        }
    }
}

// ---------------- int8 quantized v: 64-B rows = 40 int8 + half scale @ +40 ----------------

__device__ __forceinline__ void quant_store_row(float res, int lane, int r,
                                                unsigned char* __restrict__ out8) {
    float m = (lane < NCLASS) ? fabsf(res) : 0.f;
#pragma unroll
    for (int off = 32; off > 0; off >>= 1)
        m = fmaxf(m, __shfl_xor(m, off, 64));
    float inv = (m > 0.f) ? 127.0f / m : 0.f;
    if (lane < NCLASS) {
        int q = (int)lrintf(res * inv);
        out8[(size_t)r * 64 + lane] = (unsigned char)(signed char)q;
    }
    if (lane == 0)
        *(__half*)(out8 + (size_t)r * 64 + 40) = (__half)(m * (1.0f / 127.0f));
}

__global__ __launch_bounds__(256) void quant_h(const float* __restrict__ h,
                                               unsigned char* __restrict__ out8) {
    int r = (blockIdx.x * 256 + threadIdx.x) >> 6;
    int lane = threadIdx.x & 63;
    if (r >= N_NODES) return;
    int lb = lane < NCLASS ? lane : NCLASS - 1;
    float res = h[(size_t)r * NCLASS + lb];
    quant_store_row(res, lane, r, out8);
}

// out = 0.5*dinv[r]*(v[r]+sum v[c]) + 0.5*h[r], v stored int8+scale
__global__ __launch_bounds__(256) void spmm_q(const unsigned char* __restrict__ v8,
                                              const float* __restrict__ h,
                                              const int* __restrict__ rowptr,
                                              const int* __restrict__ colidx,
                                              const float* __restrict__ dinv,
                                              unsigned char* __restrict__ out8,
                                              float* __restrict__ outF,
                                              int final_it) {
    int r = (blockIdx.x * 256 + threadIdx.x) >> 6;  // one wave per row
    int lane = threadIdx.x & 63;
    if (r >= N_NODES) return;
    int lb = lane < NCLASS ? lane : NCLASS - 1;
    int s = rowptr[r], e = rowptr[r + 1];
    const unsigned char* vr = v8 + (size_t)r * 64;
    float a[8];
    a[0] = (float)(signed char)vr[lb] * (float)*(const __half*)(vr + 40);  // self
#pragma unroll
    for (int u = 1; u < 8; u++) a[u] = 0.f;
    int i = s;
    for (; i + 8 <= e; i += 8) {
        int c[8];
#pragma unroll
        for (int u = 0; u < 8; u++) c[u] = colidx[i + u];
#pragma unroll
        for (int u = 0; u < 8; u++) {
            const unsigned char* vc = v8 + (size_t)c[u] * 64;
            a[u] += (float)(signed char)vc[lb] * (float)*(const __half*)(vc + 40);
        }
    }
    for (; i < e; i++) {
        const unsigned char* vc = v8 + (size_t)colidx[i] * 64;
        a[0] += (float)(signed char)vc[lb] * (float)*(const __half*)(vc + 40);
    }
    float tot = ((a[0] + a[1]) + (a[2] + a[3])) + ((a[4] + a[5]) + (a[6] + a[7]));
    float res = 0.5f * dinv[r] * tot + 0.5f * h[(size_t)r * NCLASS + lb];
    if (final_it) {
        if (lane < NCLASS) outF[(size_t)r * NCLASS + lane] = res;
        return;
    }
    quant_store_row(res, lane, r, out8);
}

// ---------------- launch ----------------

static inline size_t align256(size_t x) { return (x + 255) & ~(size_t)255; }

extern "C" void kernel_launch(void* const* d_in, const int* in_sizes, int n_in,
                              void* d_out, int out_size, void* d_ws, size_t ws_size,
                              hipStream_t stream) {
    const float* x  = (const float*)d_in[0];
    const int*   ei = (const int*)d_in[1];
    const float* W1 = (const float*)d_in[2];
    const float* b1 = (const float*)d_in[3];
    const float* W2 = (const float*)d_in[4];
    const float* b2 = (const float*)d_in[5];
    const float* W3 = (const float*)d_in[6];
    const float* b3 = (const float*)d_in[7];
    float* out = (float*)d_out;
    const int* rows = ei;
    const int* cols = ei + N_EDGES;

    // workspace carve: fixed-size tail first, hid1/hid2 take the remainder
    char* p = (char*)d_ws;
    float* h   = (float*)p;            p += align256((size_t)N_NODES * NCLASS * 4); // 16 MB
    unsigned char* v8a = (unsigned char*)p;  p += align256((size_t)N_NODES * 64);   // 6.4 MB
    unsigned char* v8b = (unsigned char*)p;  p += align256((size_t)N_NODES * 64);   // 6.4 MB
    bf16* W1b  = (bf16*)p;    p += align256((size_t)NHID * NFEAT * 2);
    bf16* W2b  = (bf16*)p;    p += align256((size_t)NHID * NHID * 2);
    bf16* W3p  = (bf16*)p;    p += align256((size_t)64 * NHID * 2);
    float* b3p = (float*)p;   p += align256(64 * 4);
    int* cnt    = (int*)p;    p += align256((size_t)NPAD * 4);
    int* rowptr = (int*)p;    p += align256((size_t)(NPAD + 1) * 4);
    int* cursor = (int*)p;    p += align256((size_t)N_NODES * 4);
    int* colidx = (int*)p;    p += align256((size_t)N_EDGES * 4);
    int* bsum   = (int*)p;    p += align256(512 * 4);
    float* dinv = (float*)p;  p += align256((size_t)N_NODES * 4);

    size_t used = (size_t)(p - (char*)d_ws);
    size_t remain = (ws_size > used) ? (ws_size - used) : 0;
    long long cr = (long long)(remain / 2 / (NHID * 2));
    cr = (cr / 128) * 128;
    if (cr > N_NODES) cr = ((N_NODES + 127) / 128) * 128;
    if (cr < 25088) cr = 25088;  // proven to fit in earlier rounds
    int chunk = (int)cr;
    bf16* hid1 = (bf16*)p;
    bf16* hid2 = hid1 + (size_t)chunk * NHID;

    // CSR build
    init_cnt<<<NPAD / 256, 256, 0, stream>>>(cnt);
    count_edges<<<(N_EDGES + 255) / 256, 256, 0, stream>>>(rows, cnt);
    reduce_blocks<<<NB, 256, 0, stream>>>(cnt, bsum);
    scan_bsums<<<1, 512, 0, stream>>>(bsum);
    scan_write<<<NB, 256, 0, stream>>>(cnt, bsum, rowptr, cursor, dinv);
    scatter_edges<<<(N_EDGES + 255) / 256, 256, 0, stream>>>(rows, cols, cursor, colidx);

    // weight conversion
    cvt_f2b<<<(NHID * NFEAT + 255) / 256, 256, 0, stream>>>(W1, W1b, NHID * NFEAT);
    cvt_f2b<<<(NHID * NHID + 255) / 256, 256, 0, stream>>>(W2, W2b, NHID * NHID);
    pad_w3<<<(64 * NHID) / 256, 256, 0, stream>>>(W3, b3, W3p, b3p);

    // MLP in row chunks
    for (int off = 0; off < N_NODES; off += chunk) {
        int Mc = (N_NODES - off < chunk) ? (N_NODES - off) : chunk;
        int gy = (Mc + 127) / 128;
        dim3 g12(2, gy);
        gemm_mfma<128, float, true, 0><<<g12, 256, 0, stream>>>(
            x + (size_t)off * NFEAT, W1b, b1, hid1, nullptr, Mc, NFEAT, NHID);
        gemm_mfma<128, bf16, true, 0><<<g12, 256, 0, stream>>>(
            hid1, W2b, b2, hid2, nullptr, Mc, NHID, NHID);
        dim3 g3(1, gy);
        gemm_mfma<64, bf16, false, 1><<<g3, 256, 0, stream>>>(
            hid2, W3p, b3p, nullptr, h + (size_t)off * NCLASS, Mc, NHID, 64);
    }

    // quantize h -> v8a (int8 + per-row scale)
    quant_h<<<(N_NODES * 64 + 255) / 256, 256, 0, stream>>>(h, v8a);

    // 10 power iterations on int8 v
    const unsigned char* src = v8a;
    for (int it = 0; it < 10; it++) {
        int fin = (it == 9);
        unsigned char* dst = (it & 1) ? v8a : v8b;
        spmm_q<<<(N_NODES * 64 + 255) / 256, 256, 0, stream>>>(
            src, h, rowptr, colidx, dinv, dst, out, fin);
        src = dst;
    }
}